// Round 1
// baseline (596.170 us; speedup 1.0000x reference)
//
#include <hip/hip_runtime.h>

#define BEV_H 512
#define BEV_W 512
#define BEV_HW (BEV_H * BEV_W)
#define NB 8
#define NP 30000
#define NC 64

// Phase 2: record, per BEV cell, the highest pillar index p that maps to it.
// Matches numpy/JAX-CPU scatter "last write wins" semantics (highest p wins).
__global__ void scatter_winner_kernel(const int* __restrict__ coords,
                                      int* __restrict__ winner) {
    int idx = blockIdx.x * blockDim.x + threadIdx.x;   // over NB*NP
    if (idx >= NB * NP) return;
    int b = idx / NP;
    int p = idx - b * NP;
    int2 c2 = ((const int2*)coords)[idx];              // coords[b][p][{x,y}]
    int gx = c2.x;
    int gy = c2.y;
    if (gx >= 0 && gx < BEV_W && gy >= 0 && gy < BEV_H) {
        atomicMax(&winner[b * BEV_HW + gy * BEV_W + gx], p);
    }
}

// Phase 3: for every (b, c, cell) write feat[b, winner, c] or 0.
// Thread handles 4 consecutive cells for one (b,c): int4 winner load,
// up to 4 scalar feature gathers, one coalesced float4 store.
__global__ void gather_out_kernel(const float* __restrict__ feat,
                                  const int* __restrict__ winner,
                                  float* __restrict__ out) {
    int bc = blockIdx.y;                       // b*NC + c
    int b  = bc >> 6;                          // / NC
    int c  = bc & (NC - 1);
    int cell = (blockIdx.x * blockDim.x + threadIdx.x) << 2;  // 4 cells/thread

    const int4 w4 = *(const int4*)(winner + (size_t)b * BEV_HW + cell);
    const float* fb = feat + (size_t)b * NP * NC + c;

    float4 v;
    v.x = (w4.x >= 0) ? fb[(size_t)w4.x * NC] : 0.0f;
    v.y = (w4.y >= 0) ? fb[(size_t)w4.y * NC] : 0.0f;
    v.z = (w4.z >= 0) ? fb[(size_t)w4.z * NC] : 0.0f;
    v.w = (w4.w >= 0) ? fb[(size_t)w4.w * NC] : 0.0f;

    *(float4*)(out + (size_t)bc * BEV_HW + cell) = v;
}

extern "C" void kernel_launch(void* const* d_in, const int* in_sizes, int n_in,
                              void* d_out, int out_size, void* d_ws, size_t ws_size,
                              hipStream_t stream) {
    const float* feat   = (const float*)d_in[0];   // (8, 30000, 64) f32
    const int*   coords = (const int*)d_in[1];     // (8, 30000, 2) i32
    float*       out    = (float*)d_out;           // (8, 64, 512, 512) f32
    int*         winner = (int*)d_ws;              // NB*BEV_HW ints = 8 MB

    // Phase 1: winner = -1 everywhere (0xFF bytes). Capturable memset node.
    hipMemsetAsync(winner, 0xFF, (size_t)NB * BEV_HW * sizeof(int), stream);

    // Phase 2: atomicMax scatter of pillar indices.
    {
        int total = NB * NP;
        int block = 256;
        int grid  = (total + block - 1) / block;
        scatter_winner_kernel<<<grid, block, 0, stream>>>(coords, winner);
    }

    // Phase 3: gather + coalesced write of the full (8,64,512,512) output.
    {
        dim3 block(256, 1, 1);
        dim3 grid(BEV_HW / (4 * 256), NB * NC, 1);   // 256 x 512 blocks
        gather_out_kernel<<<grid, block, 0, stream>>>(feat, winner, out);
    }
}